// Round 24
// baseline (102.947 us; speedup 1.0000x reference)
//
#include <hip/hip_runtime.h>
#include <hip/hip_bf16.h>
#include <math.h>
#include <stdint.h>

#define N_NODES 100000
#define N_EDGES 1600000
#define IN_DIM 256
#define OUT_DIM 64

#define CWIN  64                          // nodes per window
#define NCB   1563                        // ceil(100000/64)
#define NPART 256                         // 256 * 6250 = 1.6M exact
#define EPP   (N_EDGES / NPART)           // 6250
#define EBCAP 1536                        // fixed window capacity
#define MAXE  EBCAP

#define GEMM_BLKS ((N_NODES + 255) / 256) // 391 blocks x 256 nodes (16 waves)
#define NTILE (N_NODES / 16)              // 6250 packer tiles (exact)

// Wh stored PERMUTED: Wh'[row][cl*4+nt] = Wh[row][nt*16+cl]
// hP: per 16-row tile, 512 cells of 8 bf16; cell = j*64 + (g*16+cl) so the
//     gemm A-load at (j) is hP + T*8KB + j*1KB + lane*16B  (fully sequential)
// WB: W in B-frag layout, cell = k16*64 + col.

typedef __attribute__((ext_vector_type(8))) short bh8;   // 8 x bf16 frag
typedef __attribute__((ext_vector_type(4))) float f4;    // mfma accumulator

typedef __attribute__((address_space(1))) const void GV;
typedef __attribute__((address_space(3))) void LV;

static __device__ __forceinline__ unsigned short f2bf(float f) {
    unsigned u = __float_as_uint(f);
    unsigned r = (u + 0x7FFFu + ((u >> 16) & 1u)) >> 16;
    return (unsigned short)r;
}

// ---------------------------------------------------------------------------
// Packer: LDS tiled transpose h (f32 row-major) -> hP (bf16 frag order).
// Both HBM sides fully coalesced. Blocks >= NTILE do W -> WB frag layout.
// ---------------------------------------------------------------------------
__global__ __launch_bounds__(256) void gat_pack(
    const float* __restrict__ h, unsigned short* __restrict__ hP,
    const float* __restrict__ W, unsigned short* __restrict__ WB)
{
    const int t = threadIdx.x;

    if (blockIdx.x >= NTILE) {            // ---- W role: 8 blocks = 2048 cells
        const int cell = (blockIdx.x - NTILE) * 256 + t;
        const int col = cell & 63;
        const int k16 = cell >> 6;        // 0..31
        const float4 lo = *(const float4*)(W + col * IN_DIM + k16 * 8);
        const float4 hi = *(const float4*)(W + col * IN_DIM + k16 * 8 + 4);
        unsigned short tmp[8];
        tmp[0] = f2bf(lo.x); tmp[1] = f2bf(lo.y);
        tmp[2] = f2bf(lo.z); tmp[3] = f2bf(lo.w);
        tmp[4] = f2bf(hi.x); tmp[5] = f2bf(hi.y);
        tmp[6] = f2bf(hi.z); tmp[7] = f2bf(hi.w);
        *(uint4*)&WB[(size_t)cell * 8] = *(uint4*)tmp;
        return;
    }

    // ---- tile role: 16 rows (16 KB) ----
    __shared__ float lds[16 * 260];       // stride 260 f32 -> 2-way banks (free)
    const size_t base = (size_t)blockIdx.x * 16 * IN_DIM;

    #pragma unroll
    for (int it = 0; it < 4; ++it) {
        const int idx = it * 256 + t;     // float4 index, 1024 total
        const float4 v = *(const float4*)(h + base + (size_t)idx * 4);
        const int row = idx >> 6;         // 64 float4 per row
        const int coloff = (idx & 63) * 4;
        *(float4*)&lds[row * 260 + coloff] = v;
    }
    __syncthreads();

    #pragma unroll
    for (int cc = 0; cc < 2; ++cc) {
        const int c = t + cc * 256;       // cell 0..511
        const int cl = c & 15;
        const int g  = (c >> 4) & 3;
        const int j  = c >> 6;
        const float* s = &lds[cl * 260 + j * 32 + g * 8];
        unsigned short tmp[8];
        #pragma unroll
        for (int x = 0; x < 8; ++x) tmp[x] = f2bf(s[x]);
        *(uint4*)&hP[(size_t)blockIdx.x * 4096 + (size_t)c * 8] = *(uint4*)tmp;
    }
}

// ---------------------------------------------------------------------------
// MEGA (bf path): gemm reads hP sequentially; W via DMA from WB.
// Scatter role (blocks >= GEMM_BLKS) = R23 two-level reservation.
// ---------------------------------------------------------------------------
__global__ __launch_bounds__(1024) void gat_mega_bf(
    const unsigned short* __restrict__ hP, const unsigned short* __restrict__ WB,
    const float* __restrict__ a, unsigned short* __restrict__ WhB,
    float* __restrict__ p_src, float* __restrict__ p_dst,
    const int* __restrict__ src, const int* __restrict__ dst,
    int* __restrict__ gcur, int* __restrict__ ebufA)
{
    __shared__ __align__(16) unsigned short Wlds[64 * 256];   // 32 KB

    const int t = threadIdx.x;

    if (blockIdx.x >= GEMM_BLKS) {        // ---- scatter role ----
        const int part = blockIdx.x - GEMM_BLKS;
        int* lh   = (int*)Wlds;
        int* lcur = ((int*)Wlds) + NCB;

        for (int i = t; i < NCB; i += 1024) lh[i] = 0;
        __syncthreads();
        const int e0 = part * EPP;
        for (int e = e0 + t; e < e0 + EPP; e += 1024)
            atomicAdd(&lh[dst[e] >> 6], 1);
        __syncthreads();
        for (int i = t; i < NCB; i += 1024) {
            const int c = lh[i];
            lcur[i] = c ? atomicAdd(&gcur[i], c) : 0;
        }
        __syncthreads();
        for (int e = e0 + t; e < e0 + EPP; e += 1024) {
            const int se = src[e], de = dst[e];
            const int w = de >> 6;
            const int off = atomicAdd(&lcur[w], 1);
            ebufA[w * EBCAP + off] = se | ((de & (CWIN - 1)) << 17);
        }
        return;
    }

    // ---- gemm role ----
    const int lane = t & 63;
    const int wv = t >> 6;                 // 0..15
    const int cl = lane & 15;
    const int g  = lane >> 4;
    const int node0 = blockIdx.x * 256 + wv * 16;

    // stage W via DMA (16 waves x 2 x 1KB, frag-layout linear copy)
    #pragma unroll
    for (int i = 0; i < 2; ++i) {
        const int chunk = wv * 2 + i;
        __builtin_amdgcn_global_load_lds(
            (GV*)(WB + chunk * 512 + lane * 8),
            (LV*)(((char*)Wlds) + chunk * 1024), 16, 0, 0);
    }
    __syncthreads();

    int T = blockIdx.x * 16 + wv;
    T = (T < NTILE) ? T : NTILE - 1;       // tail waves clamp (results discarded)
    const unsigned short* __restrict__ hpw = hP + (size_t)T * 4096;

    f4 acc[4];
    #pragma unroll
    for (int nt = 0; nt < 4; ++nt) acc[nt] = (f4){0.f, 0.f, 0.f, 0.f};

    #pragma unroll
    for (int j = 0; j < 8; ++j) {
        const bh8 af = *(const bh8*)&hpw[j * 512 + lane * 8];   // 1KB/instr stream
        #pragma unroll
        for (int nt = 0; nt < 4; ++nt) {
            const bh8 bf = *(const bh8*)&Wlds[(((j * 4 + g) * 64) + nt * 16 + cl) * 8];
            acc[nt] = __builtin_amdgcn_mfma_f32_16x16x32_bf16(af, bf, acc[nt], 0, 0, 0);
        }
    }

    float aS[4], aD[4];
    #pragma unroll
    for (int nt = 0; nt < 4; ++nt) {
        aS[nt] = a[nt * 16 + cl];
        aD[nt] = a[OUT_DIM + nt * 16 + cl];
    }

    #pragma unroll
    for (int r = 0; r < 4; ++r) {
        const int orow = node0 + g * 4 + r;
        float ps = 0.f, pd = 0.f;
        #pragma unroll
        for (int nt = 0; nt < 4; ++nt) {
            ps = fmaf(acc[nt][r], aS[nt], ps);
            pd = fmaf(acc[nt][r], aD[nt], pd);
        }
        #pragma unroll
        for (int o = 8; o > 0; o >>= 1) {
            ps += __shfl_xor(ps, o);
            pd += __shfl_xor(pd, o);
        }
        if (orow < N_NODES) {
            const unsigned lo2 = (unsigned)f2bf(acc[0][r]) |
                                 ((unsigned)f2bf(acc[1][r]) << 16);
            const unsigned hi2 = (unsigned)f2bf(acc[2][r]) |
                                 ((unsigned)f2bf(acc[3][r]) << 16);
            *(uint2*)&WhB[(size_t)orow * OUT_DIM + cl * 4] = make_uint2(lo2, hi2);
            if (cl == 0) { p_src[orow] = ps; p_dst[orow] = pd; }
        }
    }
}

// ---------------------------------------------------------------------------
// MEGA (f32 fallback = R23, used when ws too small for hP).
// ---------------------------------------------------------------------------
__global__ __launch_bounds__(1024) void gat_mega_f32(
    const float* __restrict__ h, const float* __restrict__ W,
    const float* __restrict__ a, unsigned short* __restrict__ WhB,
    float* __restrict__ p_src, float* __restrict__ p_dst,
    const int* __restrict__ src, const int* __restrict__ dst,
    int* __restrict__ gcur, int* __restrict__ ebufA)
{
    __shared__ __align__(16) unsigned short Wlds[64 * 256];

    const int t = threadIdx.x;

    if (blockIdx.x >= GEMM_BLKS) {
        const int part = blockIdx.x - GEMM_BLKS;
        int* lh   = (int*)Wlds;
        int* lcur = ((int*)Wlds) + NCB;
        for (int i = t; i < NCB; i += 1024) lh[i] = 0;
        __syncthreads();
        const int e0 = part * EPP;
        for (int e = e0 + t; e < e0 + EPP; e += 1024)
            atomicAdd(&lh[dst[e] >> 6], 1);
        __syncthreads();
        for (int i = t; i < NCB; i += 1024) {
            const int c = lh[i];
            lcur[i] = c ? atomicAdd(&gcur[i], c) : 0;
        }
        __syncthreads();
        for (int e = e0 + t; e < e0 + EPP; e += 1024) {
            const int se = src[e], de = dst[e];
            const int w = de >> 6;
            const int off = atomicAdd(&lcur[w], 1);
            ebufA[w * EBCAP + off] = se | ((de & (CWIN - 1)) << 17);
        }
        return;
    }

    const int lane = t & 63;
    const int wv = t >> 6;
    const int cl = lane & 15;
    const int g  = lane >> 4;
    const int node0 = blockIdx.x * 256 + wv * 16;

    #pragma unroll
    for (int cc = 0; cc < 2; ++cc) {
        const int cell = t + cc * 1024;
        const int col = cell & 63;
        const int k16 = cell >> 6;
        const float4 lo = *(const float4*)(W + col * IN_DIM + k16 * 8);
        const float4 hi = *(const float4*)(W + col * IN_DIM + k16 * 8 + 4);
        unsigned short tmp[8];
        tmp[0] = f2bf(lo.x); tmp[1] = f2bf(lo.y);
        tmp[2] = f2bf(lo.z); tmp[3] = f2bf(lo.w);
        tmp[4] = f2bf(hi.x); tmp[5] = f2bf(hi.y);
        tmp[6] = f2bf(hi.z); tmp[7] = f2bf(hi.w);
        *(uint4*)&Wlds[cell * 8] = *(uint4*)tmp;
    }
    __syncthreads();

    int row = node0 + cl;
    row = (row < N_NODES) ? row : N_NODES - 1;
    const float* __restrict__ hp = h + (size_t)row * IN_DIM + g * 8;

    f4 acc[4];
    #pragma unroll
    for (int nt = 0; nt < 4; ++nt) acc[nt] = (f4){0.f, 0.f, 0.f, 0.f};

    #pragma unroll
    for (int j = 0; j < 8; ++j) {
        const float4 lo = *(const float4*)(hp + j * 32);
        const float4 hi = *(const float4*)(hp + j * 32 + 4);
        bh8 af;
        af[0] = (short)f2bf(lo.x); af[1] = (short)f2bf(lo.y);
        af[2] = (short)f2bf(lo.z); af[3] = (short)f2bf(lo.w);
        af[4] = (short)f2bf(hi.x); af[5] = (short)f2bf(hi.y);
        af[6] = (short)f2bf(hi.z); af[7] = (short)f2bf(hi.w);
        #pragma unroll
        for (int nt = 0; nt < 4; ++nt) {
            const bh8 bf = *(const bh8*)&Wlds[(((j * 4 + g) * 64) + nt * 16 + cl) * 8];
            acc[nt] = __builtin_amdgcn_mfma_f32_16x16x32_bf16(af, bf, acc[nt], 0, 0, 0);
        }
    }

    float aS[4], aD[4];
    #pragma unroll
    for (int nt = 0; nt < 4; ++nt) {
        aS[nt] = a[nt * 16 + cl];
        aD[nt] = a[OUT_DIM + nt * 16 + cl];
    }

    #pragma unroll
    for (int r = 0; r < 4; ++r) {
        const int orow = node0 + g * 4 + r;
        float ps = 0.f, pd = 0.f;
        #pragma unroll
        for (int nt = 0; nt < 4; ++nt) {
            ps = fmaf(acc[nt][r], aS[nt], ps);
            pd = fmaf(acc[nt][r], aD[nt], pd);
        }
        #pragma unroll
        for (int o = 8; o > 0; o >>= 1) {
            ps += __shfl_xor(ps, o);
            pd += __shfl_xor(pd, o);
        }
        if (orow < N_NODES) {
            const unsigned lo2 = (unsigned)f2bf(acc[0][r]) |
                                 ((unsigned)f2bf(acc[1][r]) << 16);
            const unsigned hi2 = (unsigned)f2bf(acc[2][r]) |
                                 ((unsigned)f2bf(acc[3][r]) << 16);
            *(uint2*)&WhB[(size_t)orow * OUT_DIM + cl * 4] = make_uint2(lo2, hi2);
            if (cl == 0) { p_src[orow] = ps; p_dst[orow] = pd; }
        }
    }
}

// ---------------------------------------------------------------------------
// Fused node-sort + aggregation (unchanged from R23).
// ---------------------------------------------------------------------------
__global__ __launch_bounds__(256) void gat_agg_fused(
    const int* __restrict__ ebufA, const int* __restrict__ gcnt,
    const float* __restrict__ p_src, const float* __restrict__ p_dst,
    const unsigned short* __restrict__ Wh, float* __restrict__ out)
{
    __shared__ int2 ledge[MAXE];
    __shared__ int lhist[CWIN], lbase[CWIN];
    __shared__ float pdl[CWIN];

    const int t = threadIdx.x;
    const int cb = blockIdx.x;
    const int a0 = cb * EBCAP;
    const int cnt = min(gcnt[cb], MAXE);
    const int wbase = cb * CWIN;

    if (t < CWIN) {
        lhist[t] = 0;
        const int node = wbase + t;
        pdl[t] = (node < N_NODES) ? p_dst[node] : 0.f;
    }
    __syncthreads();

    int   ev[6], rk[6];
    float ps[6];
    #pragma unroll
    for (int j = 0; j < 6; ++j) {
        const int i = t + j * 256;
        ev[j] = 0; rk[j] = 0; ps[j] = 0.f;
        if (i < cnt) {
            const int e = ebufA[a0 + i];
            ev[j] = e;
            ps[j] = p_src[e & 0x1FFFF];
            rk[j] = atomicAdd(&lhist[(e >> 17) & (CWIN - 1)], 1);
        }
    }
    __syncthreads();

    if (t < 64) {
        const int own = lhist[t];
        int val = own;
        #pragma unroll
        for (int s = 1; s < 64; s <<= 1) {
            const int n = __shfl_up(val, s);
            if (t >= s) val += n;
        }
        lbase[t] = val - own;
    }
    __syncthreads();

    #pragma unroll
    for (int j = 0; j < 6; ++j) {
        const int i = t + j * 256;
        if (i < cnt) {
            const int e = ev[j];
            const int ln = (e >> 17) & (CWIN - 1);
            const float ex = __expf(fmaxf(ps[j] + pdl[ln], 0.f));
            ledge[lbase[ln] + rk[j]] = make_int2(e & 0x1FFFF, __float_as_int(ex));
        }
    }
    __syncthreads();

    const int lane = t & 63;
    const int wv = t >> 6;
    const int grp = lane >> 4;
    const int ci = lane & 15;
    const int c4 = ci * 4;

    #pragma unroll
    for (int rr = 0; rr < 4; ++rr) {
        const int ln = wv * 16 + rr * 4 + grp;
        const int node = wbase + ln;
        const int sb = lbase[ln];
        const int d  = (node < N_NODES) ? lhist[ln] : 0;

        float ssum = 0.f;
        float a0f = 0.f, a1f = 0.f, a2f = 0.f, a3f = 0.f;

        #pragma unroll 4
        for (int k = 0; k < d; ++k) {
            const int2 ed = ledge[sb + k];
            const float ex = __int_as_float(ed.y);
            const uint2 wr = *(const uint2*)(Wh + (size_t)ed.x * OUT_DIM + c4);
            ssum += ex;
            a0f = fmaf(ex, __uint_as_float(wr.x << 16), a0f);
            a1f = fmaf(ex, __uint_as_float(wr.x & 0xFFFF0000u), a1f);
            a2f = fmaf(ex, __uint_as_float(wr.y << 16), a2f);
            a3f = fmaf(ex, __uint_as_float(wr.y & 0xFFFF0000u), a3f);
        }

        if (node < N_NODES) {
            const float inv = (d > 0) ? 1.f / ssum : 0.f;
            float* ob = out + (size_t)node * OUT_DIM;
            ob[ci]      = a0f * inv;
            ob[16 + ci] = a1f * inv;
            ob[32 + ci] = a2f * inv;
            ob[48 + ci] = a3f * inv;
        }
    }
}

// ---------------------------------------------------------------------------
extern "C" void kernel_launch(void* const* d_in, const int* in_sizes, int n_in,
                              void* d_out, int out_size, void* d_ws, size_t ws_size,
                              hipStream_t stream)
{
    const float* h  = (const float*)d_in[0];
    const int* src  = (const int*)d_in[1];
    const int* dst  = (const int*)d_in[2];
    const float* W  = (const float*)d_in[3];
    const float* a  = (const float*)d_in[4];
    float* out = (float*)d_out;

    // layout (bytes): common part ends at 23,242,240; hP needs +51.2MB
    char* ws = (char*)d_ws;
    unsigned short* WhB = (unsigned short*)(ws);      // 12,800,000 (bf16, permuted)
    float* p_src   = (float*)(ws + 12800000);         //    400,000
    float* p_dst   = (float*)(ws + 13200000);         //    400,000
    int*   gcur    = (int*)  (ws + 13600000);         //      6,252
    int*   ebufA   = (int*)  (ws + 13606400);         //  9,603,072
    unsigned short* WB = (unsigned short*)(ws + 23209472); // 32,768
    unsigned short* hP = (unsigned short*)(ws + 23242240); // 51,200,000
    const size_t NEED = 23242240ull + 51200000ull;    // 74,442,240

    hipMemsetAsync(gcur, 0, NCB * sizeof(int), stream);

    if (ws_size >= NEED) {
        gat_pack<<<NTILE + 8, 256, 0, stream>>>(h, hP, W, WB);
        gat_mega_bf<<<GEMM_BLKS + NPART, 1024, 0, stream>>>(
            hP, WB, a, WhB, p_src, p_dst, src, dst, gcur, ebufA);
    } else {
        gat_mega_f32<<<GEMM_BLKS + NPART, 1024, 0, stream>>>(
            h, W, a, WhB, p_src, p_dst, src, dst, gcur, ebufA);
    }
    gat_agg_fused<<<NCB, 256, 0, stream>>>(ebufA, gcur, p_src, p_dst, WhB, out);
}

// Round 25
// 85.864 us; speedup vs baseline: 1.1989x; 1.1989x over previous
//
#include <hip/hip_runtime.h>
#include <hip/hip_bf16.h>
#include <math.h>
#include <stdint.h>

#define N_NODES 100000
#define N_EDGES 1600000
#define IN_DIM 256
#define OUT_DIM 64

#define CWIN  64                          // nodes per window
#define NCB   1563                        // ceil(100000/64)
#define NPART 256                         // 256 * 6250 = 1.6M exact
#define EPP   (N_EDGES / NPART)           // 6250
#define EBCAP 1536                        // fixed window capacity (mean 1024 + 16σ)
#define MAXE  EBCAP

#define GEMM_BLKS ((N_NODES + 255) / 256) // 391 blocks x 256 nodes (16 waves)

// ebufA layout: [window][EBCAP]; gcur[w] = edge count of window w (post-mega).
// Wh stored PERMUTED: Wh'[row][cl*4+nt] = Wh[row][nt*16+cl]

typedef __attribute__((ext_vector_type(8))) short bh8;   // 8 x bf16 frag
typedef __attribute__((ext_vector_type(4))) float f4;    // mfma accumulator

typedef __attribute__((address_space(1))) const void GV;
typedef __attribute__((address_space(3))) void LV;

// f32 -> bf16 round-to-nearest-even
static __device__ __forceinline__ unsigned short f2bf(float f) {
    unsigned u = __float_as_uint(f);
    unsigned r = (u + 0x7FFFu + ((u >> 16) & 1u)) >> 16;
    return (unsigned short)r;
}

// ---------------------------------------------------------------------------
// MEGA kernel: gemm (blocks 0..GEMM_BLKS-1) ∥ scatter (blocks GEMM_BLKS..).
// gemm: bf16 MFMA, W staged in-kernel f32->bf16 frag layout, fused p_src/
// p_dst epilogue, permuted coalesced Wh stores.
// scatter: two-level reservation CSR build -- LDS hist over 1563 windows,
// ONE global atomicAdd per (window,block) to reserve a run in the window's
// fixed-capacity region, then LDS-cursor writes. No scan, no hist kernel.
// ---------------------------------------------------------------------------
__global__ __launch_bounds__(1024) void gat_mega(
    const float* __restrict__ h, const float* __restrict__ W,
    const float* __restrict__ a, unsigned short* __restrict__ WhB,
    float* __restrict__ p_src, float* __restrict__ p_dst,
    const int* __restrict__ src, const int* __restrict__ dst,
    int* __restrict__ gcur, int* __restrict__ ebufA)
{
    __shared__ __align__(16) unsigned short Wlds[64 * 256];   // 32 KB

    const int t = threadIdx.x;

    // ---- scatter role ----
    if (blockIdx.x >= GEMM_BLKS) {
        const int part = blockIdx.x - GEMM_BLKS;
        int* lh   = (int*)Wlds;            // [NCB]
        int* lcur = ((int*)Wlds) + NCB;    // [NCB]

        for (int i = t; i < NCB; i += 1024) lh[i] = 0;
        __syncthreads();
        const int e0 = part * EPP;
        for (int e = e0 + t; e < e0 + EPP; e += 1024)
            atomicAdd(&lh[dst[e] >> 6], 1);
        __syncthreads();
        for (int i = t; i < NCB; i += 1024) {
            const int c = lh[i];
            lcur[i] = c ? atomicAdd(&gcur[i], c) : 0;   // reserve run
        }
        __syncthreads();
        for (int e = e0 + t; e < e0 + EPP; e += 1024) {
            const int se = src[e], de = dst[e];
            const int w = de >> 6;
            const int off = atomicAdd(&lcur[w], 1);     // base .. base+c
            ebufA[w * EBCAP + off] = se | ((de & (CWIN - 1)) << 17);
        }
        return;
    }

    // ---- gemm role ----
    const int lane = t & 63;
    const int wv = t >> 6;                 // 0..15
    const int cl = lane & 15;
    const int g  = lane >> 4;
    const int node0 = blockIdx.x * 256 + wv * 16;

    // stage W in-kernel: 2 frag-layout cells per thread (2048 cells total)
    #pragma unroll
    for (int cc = 0; cc < 2; ++cc) {
        const int cell = t + cc * 1024;    // 0..2047
        const int col = cell & 63;
        const int k16 = cell >> 6;         // 0..31
        const float4 lo = *(const float4*)(W + col * IN_DIM + k16 * 8);
        const float4 hi = *(const float4*)(W + col * IN_DIM + k16 * 8 + 4);
        unsigned short tmp[8];
        tmp[0] = f2bf(lo.x); tmp[1] = f2bf(lo.y);
        tmp[2] = f2bf(lo.z); tmp[3] = f2bf(lo.w);
        tmp[4] = f2bf(hi.x); tmp[5] = f2bf(hi.y);
        tmp[6] = f2bf(hi.z); tmp[7] = f2bf(hi.w);
        *(uint4*)&Wlds[cell * 8] = *(uint4*)tmp;
    }
    __syncthreads();

    int row = node0 + cl;
    row = (row < N_NODES) ? row : N_NODES - 1;
    const float* __restrict__ hp = h + (size_t)row * IN_DIM + g * 8;

    f4 acc[4];
    #pragma unroll
    for (int nt = 0; nt < 4; ++nt) acc[nt] = (f4){0.f, 0.f, 0.f, 0.f};

    #pragma unroll
    for (int j = 0; j < 8; ++j) {
        const float4 lo = *(const float4*)(hp + j * 32);
        const float4 hi = *(const float4*)(hp + j * 32 + 4);
        bh8 af;
        af[0] = (short)f2bf(lo.x); af[1] = (short)f2bf(lo.y);
        af[2] = (short)f2bf(lo.z); af[3] = (short)f2bf(lo.w);
        af[4] = (short)f2bf(hi.x); af[5] = (short)f2bf(hi.y);
        af[6] = (short)f2bf(hi.z); af[7] = (short)f2bf(hi.w);

        #pragma unroll
        for (int nt = 0; nt < 4; ++nt) {
            const bh8 bf = *(const bh8*)&Wlds[(((j * 4 + g) * 64) + nt * 16 + cl) * 8];
            acc[nt] = __builtin_amdgcn_mfma_f32_16x16x32_bf16(af, bf, acc[nt], 0, 0, 0);
        }
    }

    float aS[4], aD[4];
    #pragma unroll
    for (int nt = 0; nt < 4; ++nt) {
        aS[nt] = a[nt * 16 + cl];
        aD[nt] = a[OUT_DIM + nt * 16 + cl];
    }

    #pragma unroll
    for (int r = 0; r < 4; ++r) {
        const int orow = node0 + g * 4 + r;
        float ps = 0.f, pd = 0.f;
        #pragma unroll
        for (int nt = 0; nt < 4; ++nt) {
            ps = fmaf(acc[nt][r], aS[nt], ps);
            pd = fmaf(acc[nt][r], aD[nt], pd);
        }
        #pragma unroll
        for (int o = 8; o > 0; o >>= 1) {
            ps += __shfl_xor(ps, o);
            pd += __shfl_xor(pd, o);
        }
        if (orow < N_NODES) {
            const unsigned lo2 = (unsigned)f2bf(acc[0][r]) |
                                 ((unsigned)f2bf(acc[1][r]) << 16);
            const unsigned hi2 = (unsigned)f2bf(acc[2][r]) |
                                 ((unsigned)f2bf(acc[3][r]) << 16);
            *(uint2*)&WhB[(size_t)orow * OUT_DIM + cl * 4] = make_uint2(lo2, hi2);
            if (cl == 0) { p_src[orow] = ps; p_dst[orow] = pd; }
        }
    }
}

// ---------------------------------------------------------------------------
// Fused node-sort + aggregation. Bounds are [w*EBCAP, w*EBCAP + gcnt[w]).
// ---------------------------------------------------------------------------
__global__ __launch_bounds__(256) void gat_agg_fused(
    const int* __restrict__ ebufA, const int* __restrict__ gcnt,
    const float* __restrict__ p_src, const float* __restrict__ p_dst,
    const unsigned short* __restrict__ Wh, float* __restrict__ out)
{
    __shared__ int2 ledge[MAXE];          // 12 KB: {sv, ex_bits} binned
    __shared__ int lhist[CWIN], lbase[CWIN];
    __shared__ float pdl[CWIN];

    const int t = threadIdx.x;
    const int cb = blockIdx.x;
    const int a0 = cb * EBCAP;
    const int cnt = min(gcnt[cb], MAXE);
    const int wbase = cb * CWIN;

    if (t < CWIN) {
        lhist[t] = 0;
        const int node = wbase + t;
        pdl[t] = (node < N_NODES) ? p_dst[node] : 0.f;
    }
    __syncthreads();

    int   ev[6], rk[6];
    float ps[6];
    #pragma unroll
    for (int j = 0; j < 6; ++j) {
        const int i = t + j * 256;
        ev[j] = 0; rk[j] = 0; ps[j] = 0.f;
        if (i < cnt) {
            const int e = ebufA[a0 + i];
            ev[j] = e;
            ps[j] = p_src[e & 0x1FFFF];
            rk[j] = atomicAdd(&lhist[(e >> 17) & (CWIN - 1)], 1);
        }
    }
    __syncthreads();

    if (t < 64) {
        const int own = lhist[t];
        int val = own;
        #pragma unroll
        for (int s = 1; s < 64; s <<= 1) {
            const int n = __shfl_up(val, s);
            if (t >= s) val += n;
        }
        lbase[t] = val - own;
    }
    __syncthreads();

    #pragma unroll
    for (int j = 0; j < 6; ++j) {
        const int i = t + j * 256;
        if (i < cnt) {
            const int e = ev[j];
            const int ln = (e >> 17) & (CWIN - 1);
            const float ex = __expf(fmaxf(ps[j] + pdl[ln], 0.f));
            ledge[lbase[ln] + rk[j]] = make_int2(e & 0x1FFFF, __float_as_int(ex));
        }
    }
    __syncthreads();

    const int lane = t & 63;
    const int wv = t >> 6;
    const int grp = lane >> 4;
    const int ci = lane & 15;
    const int c4 = ci * 4;

    #pragma unroll
    for (int rr = 0; rr < 4; ++rr) {
        const int ln = wv * 16 + rr * 4 + grp;
        const int node = wbase + ln;
        const int sb = lbase[ln];
        const int d  = (node < N_NODES) ? lhist[ln] : 0;

        float ssum = 0.f;
        float a0f = 0.f, a1f = 0.f, a2f = 0.f, a3f = 0.f;

        #pragma unroll 4
        for (int k = 0; k < d; ++k) {
            const int2 ed = ledge[sb + k];
            const float ex = __int_as_float(ed.y);
            const uint2 wr = *(const uint2*)(Wh + (size_t)ed.x * OUT_DIM + c4);
            ssum += ex;
            a0f = fmaf(ex, __uint_as_float(wr.x << 16), a0f);
            a1f = fmaf(ex, __uint_as_float(wr.x & 0xFFFF0000u), a1f);
            a2f = fmaf(ex, __uint_as_float(wr.y << 16), a2f);
            a3f = fmaf(ex, __uint_as_float(wr.y & 0xFFFF0000u), a3f);
        }

        if (node < N_NODES) {
            const float inv = (d > 0) ? 1.f / ssum : 0.f;
            float* ob = out + (size_t)node * OUT_DIM;
            ob[ci]      = a0f * inv;
            ob[16 + ci] = a1f * inv;
            ob[32 + ci] = a2f * inv;
            ob[48 + ci] = a3f * inv;
        }
    }
}

// ---------------------------------------------------------------------------
extern "C" void kernel_launch(void* const* d_in, const int* in_sizes, int n_in,
                              void* d_out, int out_size, void* d_ws, size_t ws_size,
                              hipStream_t stream)
{
    const float* h  = (const float*)d_in[0];
    const int* src  = (const int*)d_in[1];
    const int* dst  = (const int*)d_in[2];
    const float* W  = (const float*)d_in[3];
    const float* a  = (const float*)d_in[4];
    float* out = (float*)d_out;

    // workspace layout (bytes), total ~23.2 MB; every buffer write-before-read
    char* ws = (char*)d_ws;
    unsigned short* WhB = (unsigned short*)(ws);      // 12,800,000 (bf16, permuted)
    float* p_src   = (float*)(ws + 12800000);         //    400,000
    float* p_dst   = (float*)(ws + 13200000);         //    400,000
    int*   gcur    = (int*)  (ws + 13600000);         //      6,252
    int*   ebufA   = (int*)  (ws + 13606252 + 4);     //  9,603,072 (NCB*EBCAP*4)

    hipMemsetAsync(gcur, 0, NCB * sizeof(int), stream);
    gat_mega<<<GEMM_BLKS + NPART, 1024, 0, stream>>>(
        h, W, a, WhB, p_src, p_dst, src, dst, gcur, ebufA);
    gat_agg_fused<<<NCB, 256, 0, stream>>>(ebufA, gcur, p_src, p_dst, WhB, out);
}

// Round 26
// 83.240 us; speedup vs baseline: 1.2367x; 1.0315x over previous
//
#include <hip/hip_runtime.h>
#include <hip/hip_bf16.h>
#include <math.h>
#include <stdint.h>

#define N_NODES 100000
#define N_EDGES 1600000
#define IN_DIM 256
#define OUT_DIM 64

#define CWIN  64                          // nodes per window
#define NCB   1563                        // ceil(100000/64)
#define NPART 256                         // 256 * 6250 = 1.6M exact
#define EPP   (N_EDGES / NPART)           // 6250
#define EBCAP 1536                        // fixed window capacity (mean 1024 + 16σ)
#define MAXE  EBCAP

#define GEMM_BLKS ((N_NODES + 511) / 512) // 196 blocks x 512 nodes (2 tiles/wave)
// total mega blocks = 196 + 256 = 452 <= 512 resident slots (2/CU @ 32KB LDS)
// -> single scheduling round, no partial-occupancy tail (R25: 647 blocks).

typedef __attribute__((ext_vector_type(8))) short bh8;   // 8 x bf16 frag
typedef __attribute__((ext_vector_type(4))) float f4;    // mfma accumulator

typedef __attribute__((address_space(1))) const void GV;
typedef __attribute__((address_space(3))) void LV;

// f32 -> bf16 round-to-nearest-even
static __device__ __forceinline__ unsigned short f2bf(float f) {
    unsigned u = __float_as_uint(f);
    unsigned r = (u + 0x7FFFu + ((u >> 16) & 1u)) >> 16;
    return (unsigned short)r;
}

// ---------------------------------------------------------------------------
// MEGA kernel: gemm (blocks 0..GEMM_BLKS-1, 512 nodes each) ∥ scatter
// (blocks GEMM_BLKS..+NPART). Inner loops byte-identical to R25; gemm wave
// runs TWO sequential 16-row tiles sharing one W staging.
// ---------------------------------------------------------------------------
__global__ __launch_bounds__(1024) void gat_mega(
    const float* __restrict__ h, const float* __restrict__ W,
    const float* __restrict__ a, unsigned short* __restrict__ WhB,
    float* __restrict__ p_src, float* __restrict__ p_dst,
    const int* __restrict__ src, const int* __restrict__ dst,
    int* __restrict__ gcur, int* __restrict__ ebufA)
{
    __shared__ __align__(16) unsigned short Wlds[64 * 256];   // 32 KB

    const int t = threadIdx.x;

    // ---- scatter role ----
    if (blockIdx.x >= GEMM_BLKS) {
        const int part = blockIdx.x - GEMM_BLKS;
        int* lh   = (int*)Wlds;            // [NCB]
        int* lcur = ((int*)Wlds) + NCB;    // [NCB]

        for (int i = t; i < NCB; i += 1024) lh[i] = 0;
        __syncthreads();
        const int e0 = part * EPP;
        for (int e = e0 + t; e < e0 + EPP; e += 1024)
            atomicAdd(&lh[dst[e] >> 6], 1);
        __syncthreads();
        for (int i = t; i < NCB; i += 1024) {
            const int c = lh[i];
            lcur[i] = c ? atomicAdd(&gcur[i], c) : 0;   // reserve run
        }
        __syncthreads();
        for (int e = e0 + t; e < e0 + EPP; e += 1024) {
            const int se = src[e], de = dst[e];
            const int w = de >> 6;
            const int off = atomicAdd(&lcur[w], 1);     // base .. base+c
            ebufA[w * EBCAP + off] = se | ((de & (CWIN - 1)) << 17);
        }
        return;
    }

    // ---- gemm role ----
    const int lane = t & 63;
    const int wv = t >> 6;                 // 0..15
    const int cl = lane & 15;
    const int g  = lane >> 4;

    // stage W once: 2 frag-layout cells per thread (2048 cells total)
    #pragma unroll
    for (int cc = 0; cc < 2; ++cc) {
        const int cell = t + cc * 1024;    // 0..2047
        const int col = cell & 63;
        const int k16 = cell >> 6;         // 0..31
        const float4 lo = *(const float4*)(W + col * IN_DIM + k16 * 8);
        const float4 hi = *(const float4*)(W + col * IN_DIM + k16 * 8 + 4);
        unsigned short tmp[8];
        tmp[0] = f2bf(lo.x); tmp[1] = f2bf(lo.y);
        tmp[2] = f2bf(lo.z); tmp[3] = f2bf(lo.w);
        tmp[4] = f2bf(hi.x); tmp[5] = f2bf(hi.y);
        tmp[6] = f2bf(hi.z); tmp[7] = f2bf(hi.w);
        *(uint4*)&Wlds[cell * 8] = *(uint4*)tmp;
    }
    __syncthreads();

    float aS[4], aD[4];
    #pragma unroll
    for (int nt = 0; nt < 4; ++nt) {
        aS[nt] = a[nt * 16 + cl];
        aD[nt] = a[OUT_DIM + nt * 16 + cl];
    }

    #pragma unroll
    for (int tt = 0; tt < 2; ++tt) {
        const int node0 = blockIdx.x * 512 + tt * 256 + wv * 16;

        int row = node0 + cl;
        row = (row < N_NODES) ? row : N_NODES - 1;
        const float* __restrict__ hp = h + (size_t)row * IN_DIM + g * 8;

        f4 acc[4];
        #pragma unroll
        for (int nt = 0; nt < 4; ++nt) acc[nt] = (f4){0.f, 0.f, 0.f, 0.f};

        #pragma unroll
        for (int j = 0; j < 8; ++j) {
            const float4 lo = *(const float4*)(hp + j * 32);
            const float4 hi = *(const float4*)(hp + j * 32 + 4);
            bh8 af;
            af[0] = (short)f2bf(lo.x); af[1] = (short)f2bf(lo.y);
            af[2] = (short)f2bf(lo.z); af[3] = (short)f2bf(lo.w);
            af[4] = (short)f2bf(hi.x); af[5] = (short)f2bf(hi.y);
            af[6] = (short)f2bf(hi.z); af[7] = (short)f2bf(hi.w);

            #pragma unroll
            for (int nt = 0; nt < 4; ++nt) {
                const bh8 bf = *(const bh8*)&Wlds[(((j * 4 + g) * 64) + nt * 16 + cl) * 8];
                acc[nt] = __builtin_amdgcn_mfma_f32_16x16x32_bf16(af, bf, acc[nt], 0, 0, 0);
            }
        }

        #pragma unroll
        for (int r = 0; r < 4; ++r) {
            const int orow = node0 + g * 4 + r;
            float ps = 0.f, pd = 0.f;
            #pragma unroll
            for (int nt = 0; nt < 4; ++nt) {
                ps = fmaf(acc[nt][r], aS[nt], ps);
                pd = fmaf(acc[nt][r], aD[nt], pd);
            }
            #pragma unroll
            for (int o = 8; o > 0; o >>= 1) {
                ps += __shfl_xor(ps, o);
                pd += __shfl_xor(pd, o);
            }
            if (orow < N_NODES) {
                const unsigned lo2 = (unsigned)f2bf(acc[0][r]) |
                                     ((unsigned)f2bf(acc[1][r]) << 16);
                const unsigned hi2 = (unsigned)f2bf(acc[2][r]) |
                                     ((unsigned)f2bf(acc[3][r]) << 16);
                *(uint2*)&WhB[(size_t)orow * OUT_DIM + cl * 4] = make_uint2(lo2, hi2);
                if (cl == 0) { p_src[orow] = ps; p_dst[orow] = pd; }
            }
        }
    }
}

// ---------------------------------------------------------------------------
// Fused node-sort + aggregation. Bounds are [w*EBCAP, w*EBCAP + gcnt[w]).
// (unchanged from R23/R25)
// ---------------------------------------------------------------------------
__global__ __launch_bounds__(256) void gat_agg_fused(
    const int* __restrict__ ebufA, const int* __restrict__ gcnt,
    const float* __restrict__ p_src, const float* __restrict__ p_dst,
    const unsigned short* __restrict__ Wh, float* __restrict__ out)
{
    __shared__ int2 ledge[MAXE];          // 12 KB: {sv, ex_bits} binned
    __shared__ int lhist[CWIN], lbase[CWIN];
    __shared__ float pdl[CWIN];

    const int t = threadIdx.x;
    const int cb = blockIdx.x;
    const int a0 = cb * EBCAP;
    const int cnt = min(gcnt[cb], MAXE);
    const int wbase = cb * CWIN;

    if (t < CWIN) {
        lhist[t] = 0;
        const int node = wbase + t;
        pdl[t] = (node < N_NODES) ? p_dst[node] : 0.f;
    }
    __syncthreads();

    int   ev[6], rk[6];
    float ps[6];
    #pragma unroll
    for (int j = 0; j < 6; ++j) {
        const int i = t + j * 256;
        ev[j] = 0; rk[j] = 0; ps[j] = 0.f;
        if (i < cnt) {
            const int e = ebufA[a0 + i];
            ev[j] = e;
            ps[j] = p_src[e & 0x1FFFF];
            rk[j] = atomicAdd(&lhist[(e >> 17) & (CWIN - 1)], 1);
        }
    }
    __syncthreads();

    if (t < 64) {
        const int own = lhist[t];
        int val = own;
        #pragma unroll
        for (int s = 1; s < 64; s <<= 1) {
            const int n = __shfl_up(val, s);
            if (t >= s) val += n;
        }
        lbase[t] = val - own;
    }
    __syncthreads();

    #pragma unroll
    for (int j = 0; j < 6; ++j) {
        const int i = t + j * 256;
        if (i < cnt) {
            const int e = ev[j];
            const int ln = (e >> 17) & (CWIN - 1);
            const float ex = __expf(fmaxf(ps[j] + pdl[ln], 0.f));
            ledge[lbase[ln] + rk[j]] = make_int2(e & 0x1FFFF, __float_as_int(ex));
        }
    }
    __syncthreads();

    const int lane = t & 63;
    const int wv = t >> 6;
    const int grp = lane >> 4;
    const int ci = lane & 15;
    const int c4 = ci * 4;

    #pragma unroll
    for (int rr = 0; rr < 4; ++rr) {
        const int ln = wv * 16 + rr * 4 + grp;
        const int node = wbase + ln;
        const int sb = lbase[ln];
        const int d  = (node < N_NODES) ? lhist[ln] : 0;

        float ssum = 0.f;
        float a0f = 0.f, a1f = 0.f, a2f = 0.f, a3f = 0.f;

        #pragma unroll 4
        for (int k = 0; k < d; ++k) {
            const int2 ed = ledge[sb + k];
            const float ex = __int_as_float(ed.y);
            const uint2 wr = *(const uint2*)(Wh + (size_t)ed.x * OUT_DIM + c4);
            ssum += ex;
            a0f = fmaf(ex, __uint_as_float(wr.x << 16), a0f);
            a1f = fmaf(ex, __uint_as_float(wr.x & 0xFFFF0000u), a1f);
            a2f = fmaf(ex, __uint_as_float(wr.y << 16), a2f);
            a3f = fmaf(ex, __uint_as_float(wr.y & 0xFFFF0000u), a3f);
        }

        if (node < N_NODES) {
            const float inv = (d > 0) ? 1.f / ssum : 0.f;
            float* ob = out + (size_t)node * OUT_DIM;
            ob[ci]      = a0f * inv;
            ob[16 + ci] = a1f * inv;
            ob[32 + ci] = a2f * inv;
            ob[48 + ci] = a3f * inv;
        }
    }
}

// ---------------------------------------------------------------------------
extern "C" void kernel_launch(void* const* d_in, const int* in_sizes, int n_in,
                              void* d_out, int out_size, void* d_ws, size_t ws_size,
                              hipStream_t stream)
{
    const float* h  = (const float*)d_in[0];
    const int* src  = (const int*)d_in[1];
    const int* dst  = (const int*)d_in[2];
    const float* W  = (const float*)d_in[3];
    const float* a  = (const float*)d_in[4];
    float* out = (float*)d_out;

    // workspace layout (bytes), total ~23.2 MB; every buffer write-before-read
    char* ws = (char*)d_ws;
    unsigned short* WhB = (unsigned short*)(ws);      // 12,800,000 (bf16, permuted)
    float* p_src   = (float*)(ws + 12800000);         //    400,000
    float* p_dst   = (float*)(ws + 13200000);         //    400,000
    int*   gcur    = (int*)  (ws + 13600000);         //      6,252
    int*   ebufA   = (int*)  (ws + 13606252 + 4);     //  9,603,072 (NCB*EBCAP*4)

    hipMemsetAsync(gcur, 0, NCB * sizeof(int), stream);
    gat_mega<<<GEMM_BLKS + NPART, 1024, 0, stream>>>(
        h, W, a, WhB, p_src, p_dst, src, dst, gcur, ebufA);
    gat_agg_fused<<<NCB, 256, 0, stream>>>(ebufA, gcur, p_src, p_dst, WhB, out);
}